// Round 11
// baseline (448.543 us; speedup 1.0000x reference)
//
#include <hip/hip_runtime.h>
#include <cstdint>
#include <cstddef>

// ---------------------------------------------------------------------------
// Problem constants
// ---------------------------------------------------------------------------
constexpr int N_CLASSES  = 10;
constexpr int N_INTERNAL = 256;
constexpr int N_VALS     = 2 * N_CLASSES + N_INTERNAL;  // 276
constexpr int B_SZ  = 8192;
constexpr int D_IN  = 784;
constexpr int KP1   = 896;    // D_IN padded to multiple of 128
constexpr int H_DIM = 4096;

// ---------------------------------------------------------------------------
// Compile-time reconstruction of np.random.RandomState(0) circuit generation.
// (verified bit-exact in round 2: absmax == 0.0)
// ---------------------------------------------------------------------------
struct MTState {
  uint32_t key[624];
  int pos;
};

constexpr uint32_t mt_next(MTState& st) {
  if (st.pos == 624) {
    for (int i = 0; i < 624; ++i) {
      uint32_t y = (st.key[i] & 0x80000000u) | (st.key[(i + 1) % 624] & 0x7fffffffu);
      st.key[i] = st.key[(i + 397) % 624] ^ (y >> 1) ^ ((y & 1u) ? 0x9908b0dfu : 0u);
    }
    st.pos = 0;
  }
  uint32_t y = st.key[st.pos++];
  y ^= y >> 11;
  y ^= (y << 7) & 0x9d2c5680u;
  y ^= (y << 15) & 0xefc60000u;
  y ^= y >> 18;
  return y;
}

constexpr uint32_t interval_draw(MTState& st, uint32_t maxv) {
  if (maxv == 0u) return 0u;
  uint32_t mask = maxv;
  mask |= mask >> 1; mask |= mask >> 2; mask |= mask >> 4;
  mask |= mask >> 8; mask |= mask >> 16;
  uint32_t v = mt_next(st) & mask;
  while (v > maxv) v = mt_next(st) & mask;
  return v;
}

struct Circuit {
  int16_t prime[N_INTERNAL][3];
  int16_t sub[N_INTERNAL][3];
};

constexpr Circuit make_circuit() {
  MTState st{};
  uint32_t s = 0u;
  for (int i = 0; i < 624; ++i) {
    st.key[i] = s;
    s = 1812433253u * (s ^ (s >> 30)) + (uint32_t)i + 1u;
  }
  st.pos = 624;

  Circuit c{};
  for (int node = 0; node < N_INTERNAL; ++node) {
    const int avail = 2 * N_CLASSES + node;
    int arr[N_CLASSES] = {0, 1, 2, 3, 4, 5, 6, 7, 8, 9};
    for (int i = N_CLASSES - 1; i >= 1; --i) {
      uint32_t j = interval_draw(st, (uint32_t)i);
      int tmp = arr[i]; arr[i] = arr[j]; arr[j] = tmp;
    }
    for (int e = 0; e < 3; ++e) c.prime[node][e] = (int16_t)arr[e];
    for (int e = 0; e < 3; ++e) c.sub[node][e] = (int16_t)interval_draw(st, (uint32_t)(avail - 1));
  }
  return c;
}

constexpr Circuit CIRC = make_circuit();

// ---------------------------------------------------------------------------
// helpers
// ---------------------------------------------------------------------------
__device__ __forceinline__ uint16_t f2bf(float f) {
  uint32_t u = __builtin_bit_cast(uint32_t, f);
  uint32_t r = (u + 0x7fffu + ((u >> 16) & 1u)) >> 16;  // RNE
  return (uint16_t)r;
}
__device__ __forceinline__ float bf2f(uint16_t h) {
  uint32_t u = ((uint32_t)h) << 16;
  return __builtin_bit_cast(float, u);
}

__device__ __forceinline__ void load_lds16(const void* g, void* l) {
  __builtin_amdgcn_global_load_lds(
      (const __attribute__((address_space(1))) unsigned int*)g,
      (__attribute__((address_space(3))) unsigned int*)l, 16, 0, 0);
}

using bf16x8 = __attribute__((ext_vector_type(8))) short;
using f32x4  = __attribute__((ext_vector_type(4))) float;
using f32x16 = __attribute__((ext_vector_type(16))) float;
using u16x8  = __attribute__((ext_vector_type(8))) unsigned short;
using u16x4  = __attribute__((ext_vector_type(4))) unsigned short;

// ds_read_b128 with compile-time offset immediate (no per-read VALU addr math)
template <int IMM>
__device__ __forceinline__ void dsr_i(bf16x8& d, uint32_t a) {
  asm volatile("ds_read_b128 %0, %1 offset:%2" : "=v"(d) : "v"(a), "n"(IMM));
}

// ---------------------------------------------------------------------------
// Circuit evaluation: fully unrolled, static indices only
// ---------------------------------------------------------------------------
template <int I>
__device__ __forceinline__ void eval_node(float (&vals)[N_VALS]) {
  if constexpr (I < N_INTERNAL) {
    constexpr int p0 = CIRC.prime[I][0], s0 = CIRC.sub[I][0];
    constexpr int p1 = CIRC.prime[I][1], s1 = CIRC.sub[I][1];
    constexpr int p2 = CIRC.prime[I][2], s2 = CIRC.sub[I][2];
    vals[2 * N_CLASSES + I] =
        vals[p0] * vals[s0] + vals[p1] * vals[s1] + vals[p2] * vals[s2];
    eval_node<I + 1>(vals);
  }
}

__global__ __launch_bounds__(256) void circuit_kernel(
    const float* __restrict__ probs, float* __restrict__ out, int B) {
  int r = blockIdx.x * blockDim.x + threadIdx.x;
  if (r >= B) return;
  float vals[N_VALS];
#pragma unroll
  for (int c = 0; c < N_CLASSES; ++c) {
    float p = probs[r * N_CLASSES + c];
    vals[c] = p;
    vals[N_CLASSES + c] = 1.0f - p;
  }
  eval_node<0>(vals);
  out[r] = vals[N_VALS - 1];
}

// ---------------------------------------------------------------------------
// x [B,784] f32 -> xb [B,896] bf16, one row per block, float4 loads (G13)
// ---------------------------------------------------------------------------
__global__ __launch_bounds__(256) void convert_pad_x(
    const float* __restrict__ x, uint16_t* __restrict__ xb) {
  const int r = blockIdx.x;
  const int t = threadIdx.x;
  if (t < D_IN / 4) {  // 196 threads convert
    float4 v = *reinterpret_cast<const float4*>(x + (size_t)r * D_IN + t * 4);
    u16x4 o;
    o[0] = f2bf(v.x); o[1] = f2bf(v.y); o[2] = f2bf(v.z); o[3] = f2bf(v.w);
    *reinterpret_cast<u16x4*>(xb + (size_t)r * KP1 + t * 4) = o;
  } else if (t < KP1 / 4) {  // threads 196..223 zero the pad
    u16x4 z = {0, 0, 0, 0};
    *reinterpret_cast<u16x4*>(xb + (size_t)r * KP1 + t * 4) = z;
  }
}

// ---------------------------------------------------------------------------
// W [K,N] f32 -> Wt [N,Kp] bf16 (transpose + convert, zero-pad k in [K,Kp))
// 64x64 tile, float4 global loads, ushort8 (16B) global stores.
// ---------------------------------------------------------------------------
__global__ __launch_bounds__(256) void transpose_convert(
    const float* __restrict__ W, uint16_t* __restrict__ Wt,
    int K, int N, int Kp) {
  __shared__ float tile[64][65];
  const int kt = blockIdx.y * 64;
  const int nt = blockIdx.x * 64;
  const int t  = threadIdx.x;

  const int lr = t >> 4;         // 0..15
  const int lc = (t & 15) * 4;   // 0..60
#pragma unroll
  for (int p = 0; p < 4; ++p) {
    const int row = lr + p * 16;
    const int k = kt + row;
    float4 v = {0.f, 0.f, 0.f, 0.f};
    if (k < K) v = *reinterpret_cast<const float4*>(W + (size_t)k * N + nt + lc);
    tile[row][lc + 0] = v.x;
    tile[row][lc + 1] = v.y;
    tile[row][lc + 2] = v.z;
    tile[row][lc + 3] = v.w;
  }
  __syncthreads();

  const int wn = t >> 3;        // 0..31
  const int k8 = (t & 7) * 8;   // 0..56
#pragma unroll
  for (int p = 0; p < 2; ++p) {
    const int n = nt + wn + 32 * p;
    u16x8 o;
#pragma unroll
    for (int i = 0; i < 8; ++i) o[i] = f2bf(tile[k8 + i][wn + 32 * p]);
    *reinterpret_cast<u16x8*>(Wt + (size_t)n * Kp + kt + k8) = o;
  }
}

// ---------------------------------------------------------------------------
// 256x256 bf16 MFMA GEMM, 32x32x16 MFMA, 4 phases/iter (2 K-tiles of BK=64):
//   C[M,N] = relu(A[M,K] @ Bt[N,K]^T + bias[N]), bf16 in/out, f32 accum.
// 512 threads = 8 waves (2Mx4N), per-wave 128x64 output = 4 row-tiles x 2
// col-tiles of 32. Each phase = 2 k-slices (K=16 each) x full wave-tile:
// 12 ds_read_b128 + 16 MFMA. vs R10's 16x16 structure: reads/K-tile 28->24,
// MFMA cycles -17% (8.07cy/32k FLOP vs 4.85/16k) — R10 was LDS-pipe-bound.
// Staging layout/addressing UNCHANGED from R10 (verified); reader addresses
// re-derived for 32-row fragments against the same row-permuted+XOR-swizzled
// LDS (spot-verified element-wise). Stages batched: ph1 = all of tile b
// (buf1, 8 loads), ph3 = all of tile c (buf0); vmcnt(0) at ph2/ph4 ends
// confirms loads issued >=1 phase (~1400cy > 900cy HBM) earlier. WAR safe:
// each staged buffer's last reader drained (lgkmcnt(0)) >=1 barrier before.
// A-frag: lane l -> row=l&31, k=(l>>5)*8+j (16x16-family pattern); C/D:
// col=lane&31, row=(reg&3)+8*(reg>>2)+4*(lane>>5) [measured m74/m101].
// VGPR: 48 frag + 8 addr + misc ~= 70 arch-VGPR + 128 AGPR acc.
// Requires: M%256==0, N%256==0, K%128==0, K>=256.
// ---------------------------------------------------------------------------
__device__ __forceinline__ f32x16 mfma32(const bf16x8& a, const bf16x8& b, const f32x16& c) {
  return __builtin_amdgcn_mfma_f32_32x32x16_bf16(a, b, c, 0, 0, 0);
}

template <int BUF, int SP, typename F>
__device__ __forceinline__ void phase32(
    const uint32_t (&aA)[4], const uint32_t (&bA)[4],
    f32x16 (&acc)[4][2], F&& stage) {
  constexpr int BO = BUF * 32768;
  bf16x8 Af[4][2], Bf[2][2];
  // A row-tiles: imm = (rt>>1)*16384 + (rt&1)*4096
  dsr_i<BO + 0>(Af[0][0], aA[SP]);     dsr_i<BO + 0>(Af[0][1], aA[SP + 1]);
  dsr_i<BO + 4096>(Af[1][0], aA[SP]);  dsr_i<BO + 4096>(Af[1][1], aA[SP + 1]);
  dsr_i<BO + 16384>(Af[2][0], aA[SP]); dsr_i<BO + 16384>(Af[2][1], aA[SP + 1]);
  dsr_i<BO + 20480>(Af[3][0], aA[SP]); dsr_i<BO + 20480>(Af[3][1], aA[SP + 1]);
  // B col-tiles: imm = ct*16384 (region base 65536 folded into bA regs)
  dsr_i<BO + 0>(Bf[0][0], bA[SP]);     dsr_i<BO + 0>(Bf[0][1], bA[SP + 1]);
  dsr_i<BO + 16384>(Bf[1][0], bA[SP]); dsr_i<BO + 16384>(Bf[1][1], bA[SP + 1]);
  // stage issues (global_load_lds) for this phase
  stage();
  // wait own LDS reads; MFMA cluster
  asm volatile("s_waitcnt lgkmcnt(0)" ::: "memory");
  __builtin_amdgcn_sched_barrier(0);  // rule #18
  __builtin_amdgcn_s_setprio(1);
#pragma unroll
  for (int sl = 0; sl < 2; ++sl)
#pragma unroll
    for (int rt = 0; rt < 4; ++rt)
#pragma unroll
      for (int ct = 0; ct < 2; ++ct)
        acc[rt][ct] = mfma32(Af[rt][sl], Bf[ct][sl], acc[rt][ct]);
  __builtin_amdgcn_s_setprio(0);
  if constexpr (SP == 2) asm volatile("s_waitcnt vmcnt(0)" ::: "memory");
  __builtin_amdgcn_s_barrier();
}

__global__ __launch_bounds__(512, 1) void gemm256_bf16(
    const uint16_t* __restrict__ A, const uint16_t* __restrict__ Bt,
    const float* __restrict__ bias, uint16_t* __restrict__ C,
    int M, int N, int K) {
  extern __shared__ char smem[];

  const int t    = threadIdx.x;
  const int t16  = t * 16;
  const int lane = t & 63;
  const int wid  = t >> 6;
  const int wr   = wid >> 2;   // 0..1
  const int wc   = wid & 3;    // 0..3
  const int l31  = lane & 31;
  const int hi   = lane >> 5;
  const int l7   = lane & 7;

  // XCD-aware bijective swizzle (nwg % 8 == 0 for both layers)
  const int gx = gridDim.x, gy = gridDim.y;
  const int nwg = gx * gy;
  const int id  = blockIdx.y * gx + blockIdx.x;
  const int cpx = nwg >> 3;
  const int sid = (id & 7) * cpx + (id >> 3);
  const int row0 = (sid / gx) * 256;
  const int col0 = (sid % gx) * 256;

  const uint32_t Kb = (uint32_t)K * 2;

  // uniform (SGPR) staging base pointers: fold row0/col0
  const char* gA = (const char*)A + (size_t)row0 * Kb;
  const char* gB = (const char*)Bt + (size_t)col0 * Kb;

  // per-lane staging source offsets (2 VGPRs): row = t>>3, slot sg  [as R10]
  const uint32_t prow = (uint32_t)(t >> 3);
  const uint32_t sg   = (uint32_t)(((t & 7) ^ (t >> 3)) & 7) * 16u;
  const uint32_t srcA = prow * Kb + sg;
  const uint32_t srcB = (prow + 32u * (prow >> 5)) * Kb + sg;

  // uniform row deltas for the (h,j) staging variants  [as R10]
#define ROWA(h, j) ((h) * 64 + (j) * 128)
#define ROWB(h, j) ((h) * 32 + (j) * 128)

#define STAGE_A(v, h, kt) do { \
    load_lds16(gA + (size_t)(kt) * 128 + (size_t)ROWA(h, 0) * Kb + srcA, \
               smem + (v) * 32768 + (h) * 16384 + t16); \
    load_lds16(gA + (size_t)(kt) * 128 + (size_t)ROWA(h, 1) * Kb + srcA, \
               smem + (v) * 32768 + (h) * 16384 + 8192 + t16); } while (0)
#define STAGE_B(v, h, kt) do { \
    load_lds16(gB + (size_t)(kt) * 128 + (size_t)ROWB(h, 0) * Kb + srcB, \
               smem + 65536 + (v) * 32768 + (h) * 16384 + t16); \
    load_lds16(gB + (size_t)(kt) * 128 + (size_t)ROWB(h, 1) * Kb + srcB, \
               smem + 65536 + (v) * 32768 + (h) * 16384 + 8192 + t16); } while (0)

  // ---- per-lane ds_read slice addresses (4 A + 4 B VGPRs)
  // A: global row wr*128+rt*32+l31 lives at LDS row (rt>>1)*128 + wr*64 +
  //    (rt&1)*32 + l31 (row-perm inverse); rt part folded into immediates.
  // slot for k-chunk (s*2+hi): ((s*2)|hi) ^ l7   (row&7 == l7 for all rt/ct)
  const uint32_t smb = (uint32_t)(size_t)(__attribute__((address_space(3))) char*)smem;
  uint32_t aA[4], bA[4];
  const uint32_t abase = smb + (uint32_t)(wr * 8192 + l31 * 128);
  const uint32_t bbase = smb + 65536u +
      (uint32_t)((wc >> 1) * 8192 + (wc & 1) * 4096 + l31 * 128);
#pragma unroll
  for (int s = 0; s < 4; ++s) {
    const uint32_t slot = (uint32_t)(((s * 2) | hi) ^ l7) * 16u;
    aA[s] = abase + slot;
    bA[s] = bbase + slot;
  }

  f32x16 acc[4][2];
#pragma unroll
  for (int rt = 0; rt < 4; ++rt)
#pragma unroll
    for (int ct = 0; ct < 2; ++ct)
#pragma unroll
      for (int e = 0; e < 16; ++e) acc[rt][ct][e] = 0.0f;

  // ---- prologue: stage tile0 -> buf0 fully; confirm; barrier
  STAGE_A(0, 0, 0); STAGE_B(0, 0, 0); STAGE_A(0, 1, 0); STAGE_B(0, 1, 0);
  asm volatile("s_waitcnt vmcnt(0)" ::: "memory");
  __builtin_amdgcn_s_barrier();

  const int NI = K >> 7;  // iterations; 2 K-tiles each
  int i = 0;
  for (; i < NI - 1; ++i) {
    const int tb = 2 * i + 1, tc = 2 * i + 2;
    phase32<0, 0>(aA, bA, acc, [&]() {
      STAGE_A(1, 0, tb); STAGE_B(1, 0, tb); STAGE_A(1, 1, tb); STAGE_B(1, 1, tb);
    });
    phase32<0, 2>(aA, bA, acc, [&]() {});
    phase32<1, 0>(aA, bA, acc, [&]() {
      STAGE_A(0, 0, tc); STAGE_B(0, 0, tc); STAGE_A(0, 1, tc); STAGE_B(0, 1, tc);
    });
    phase32<1, 2>(aA, bA, acc, [&]() {});
  }
  // peeled last iteration: stage tile b only, no tile c
  {
    const int tb = 2 * i + 1;
    phase32<0, 0>(aA, bA, acc, [&]() {
      STAGE_A(1, 0, tb); STAGE_B(1, 0, tb); STAGE_A(1, 1, tb); STAGE_B(1, 1, tb);
    });
    phase32<0, 2>(aA, bA, acc, [&]() {});
    phase32<1, 0>(aA, bA, acc, [&]() {});
    phase32<1, 2>(aA, bA, acc, [&]() {});
  }
#undef STAGE_A
#undef STAGE_B
#undef ROWA
#undef ROWB

  // ---- epilogue: bias + relu + bf16 store
  // 32x32 C/D layout: col=lane&31, row=(reg&3)+8*(reg>>2)+4*(lane>>5) [m74/m101]
#pragma unroll
  for (int rt = 0; rt < 4; ++rt)
#pragma unroll
    for (int ct = 0; ct < 2; ++ct) {
      const int col = col0 + wc * 64 + ct * 32 + l31;
      const float bv = bias[col];
#pragma unroll
      for (int reg = 0; reg < 16; ++reg) {
        const int row = row0 + wr * 128 + rt * 32 +
                        (reg & 3) + 8 * (reg >> 2) + 4 * hi;
        float v = acc[rt][ct][reg] + bv;
        v = fmaxf(v, 0.0f);
        C[(size_t)row * N + col] = f2bf(v);
      }
    }
}

// ---------------------------------------------------------------------------
// logits (K=4096, N=10) + softmax -> probs[B,10]; one wave per row; h2 bf16
// ---------------------------------------------------------------------------
__global__ __launch_bounds__(256) void logits_softmax_kernel(
    const uint16_t* __restrict__ h2, const float* __restrict__ W3,
    const float* __restrict__ b3, float* __restrict__ probs, int B) {
  const int wave = threadIdx.x >> 6;
  const int lane = threadIdx.x & 63;
  const int row  = blockIdx.x * 4 + wave;
  if (row >= B) return;

  const uint16_t* hrow = h2 + (size_t)row * H_DIM;
  float acc[N_CLASSES];
#pragma unroll
  for (int c = 0; c < N_CLASSES; ++c) acc[c] = 0.0f;

#pragma unroll
  for (int it = 0; it < H_DIM / (64 * 8); ++it) {
    const int k0 = (it * 64 + lane) * 8;
    ushort4 u0 = *reinterpret_cast<const ushort4*>(hrow + k0);
    ushort4 u1 = *reinterpret_cast<const ushort4*>(hrow + k0 + 4);
    float hv[8] = {bf2f(u0.x), bf2f(u0.y), bf2f(u0.z), bf2f(u0.w),
                   bf2f(u1.x), bf2f(u1.y), bf2f(u1.z), bf2f(u1.w)};
#pragma unroll
    for (int q = 0; q < 8; ++q) {
      const float* wrow = W3 + (size_t)(k0 + q) * N_CLASSES;
#pragma unroll
      for (int c = 0; c < N_CLASSES; ++c) acc[c] = fmaf(hv[q], wrow[c], acc[c]);
    }
  }

#pragma unroll
  for (int c = 0; c < N_CLASSES; ++c) {
#pragma unroll
    for (int s = 32; s >= 1; s >>= 1) acc[c] += __shfl_xor(acc[c], s, 64);
  }

  if (lane == 0) {
    float l[N_CLASSES], m = -3.0e38f;
#pragma unroll
    for (int c = 0; c < N_CLASSES; ++c) {
      l[c] = acc[c] + b3[c];
      m = fmaxf(m, l[c]);
    }
    float sum = 0.0f;
#pragma unroll
    for (int c = 0; c < N_CLASSES; ++c) {
      l[c] = expf(l[c] - m);
      sum += l[c];
    }
    const float inv = 1.0f / sum;
#pragma unroll
    for (int c = 0; c < N_CLASSES; ++c) probs[row * N_CLASSES + c] = l[c] * inv;
  }
}

// ---------------------------------------------------------------------------
// launch.  ws layout (bf16 unless noted), total ~182 MB:
//   xb[8192*896] w1t[4096*896] w2t[4096*4096] h1[8192*4096] h2[8192*4096]
//   probs f32[8192*10]
// ---------------------------------------------------------------------------
extern "C" void kernel_launch(void* const* d_in, const int* in_sizes, int n_in,
                              void* d_out, int out_size, void* d_ws, size_t ws_size,
                              hipStream_t stream) {
  const float* x  = (const float*)d_in[0];
  const float* W1 = (const float*)d_in[1];
  const float* b1 = (const float*)d_in[2];
  const float* W2 = (const float*)d_in[3];
  const float* b2 = (const float*)d_in[4];
  const float* W3 = (const float*)d_in[5];
  const float* b3 = (const float*)d_in[6];
  float* out = (float*)d_out;

  uint16_t* xb  = (uint16_t*)d_ws;
  uint16_t* w1t = xb  + (size_t)B_SZ * KP1;
  uint16_t* w2t = w1t + (size_t)H_DIM * KP1;
  uint16_t* h1  = w2t + (size_t)H_DIM * H_DIM;
  uint16_t* h2  = h1  + (size_t)B_SZ * H_DIM;
  float* probs  = (float*)(h2 + (size_t)B_SZ * H_DIM);

  // allow 128 KiB dynamic LDS for the GEMM (host-side attr, capture-safe)
  (void)hipFuncSetAttribute((const void*)gemm256_bf16,
                            hipFuncAttributeMaxDynamicSharedMemorySize, 131072);

  dim3 blk(256);

  // input conversions (vectorized: float4 loads, 16B bf16 stores)
  convert_pad_x<<<dim3(B_SZ), blk, 0, stream>>>(x, xb);
  transpose_convert<<<dim3(H_DIM / 64, KP1 / 64), blk, 0, stream>>>(W1, w1t, D_IN, H_DIM, KP1);
  transpose_convert<<<dim3(H_DIM / 64, H_DIM / 64), blk, 0, stream>>>(W2, w2t, H_DIM, H_DIM, H_DIM);

  // layer 1: h1 = relu(xb @ w1t^T + b1)   [8192,896]x[896,4096]
  gemm256_bf16<<<dim3(H_DIM / 256, B_SZ / 256), dim3(512), 131072, stream>>>(
      xb, w1t, b1, h1, B_SZ, H_DIM, KP1);

  // layer 2: h2 = relu(h1 @ w2t^T + b2)   [8192,4096]x[4096,4096]
  gemm256_bf16<<<dim3(H_DIM / 256, B_SZ / 256), dim3(512), 131072, stream>>>(
      h1, w2t, b2, h2, B_SZ, H_DIM, H_DIM);

  // layer 3 + softmax -> probs
  logits_softmax_kernel<<<dim3(B_SZ / 4), blk, 0, stream>>>(h2, W3, b3, probs, B_SZ);

  // circuit eval -> out[B]
  circuit_kernel<<<dim3(B_SZ / 256), blk, 0, stream>>>(probs, out, B_SZ);
}

// Round 12
// 404.716 us; speedup vs baseline: 1.1083x; 1.1083x over previous
//
#include <hip/hip_runtime.h>
#include <cstdint>
#include <cstddef>

// ---------------------------------------------------------------------------
// Problem constants
// ---------------------------------------------------------------------------
constexpr int N_CLASSES  = 10;
constexpr int N_INTERNAL = 256;
constexpr int N_VALS     = 2 * N_CLASSES + N_INTERNAL;  // 276
constexpr int B_SZ  = 8192;
constexpr int D_IN  = 784;
constexpr int KP1   = 896;    // D_IN padded to multiple of 128
constexpr int H_DIM = 4096;

// ---------------------------------------------------------------------------
// Compile-time reconstruction of np.random.RandomState(0) circuit generation.
// (verified bit-exact in round 2: absmax == 0.0)
// ---------------------------------------------------------------------------
struct MTState {
  uint32_t key[624];
  int pos;
};

constexpr uint32_t mt_next(MTState& st) {
  if (st.pos == 624) {
    for (int i = 0; i < 624; ++i) {
      uint32_t y = (st.key[i] & 0x80000000u) | (st.key[(i + 1) % 624] & 0x7fffffffu);
      st.key[i] = st.key[(i + 397) % 624] ^ (y >> 1) ^ ((y & 1u) ? 0x9908b0dfu : 0u);
    }
    st.pos = 0;
  }
  uint32_t y = st.key[st.pos++];
  y ^= y >> 11;
  y ^= (y << 7) & 0x9d2c5680u;
  y ^= (y << 15) & 0xefc60000u;
  y ^= y >> 18;
  return y;
}

constexpr uint32_t interval_draw(MTState& st, uint32_t maxv) {
  if (maxv == 0u) return 0u;
  uint32_t mask = maxv;
  mask |= mask >> 1; mask |= mask >> 2; mask |= mask >> 4;
  mask |= mask >> 8; mask |= mask >> 16;
  uint32_t v = mt_next(st) & mask;
  while (v > maxv) v = mt_next(st) & mask;
  return v;
}

struct Circuit {
  int16_t prime[N_INTERNAL][3];
  int16_t sub[N_INTERNAL][3];
};

constexpr Circuit make_circuit() {
  MTState st{};
  uint32_t s = 0u;
  for (int i = 0; i < 624; ++i) {
    st.key[i] = s;
    s = 1812433253u * (s ^ (s >> 30)) + (uint32_t)i + 1u;
  }
  st.pos = 624;

  Circuit c{};
  for (int node = 0; node < N_INTERNAL; ++node) {
    const int avail = 2 * N_CLASSES + node;
    int arr[N_CLASSES] = {0, 1, 2, 3, 4, 5, 6, 7, 8, 9};
    for (int i = N_CLASSES - 1; i >= 1; --i) {
      uint32_t j = interval_draw(st, (uint32_t)i);
      int tmp = arr[i]; arr[i] = arr[j]; arr[j] = tmp;
    }
    for (int e = 0; e < 3; ++e) c.prime[node][e] = (int16_t)arr[e];
    for (int e = 0; e < 3; ++e) c.sub[node][e] = (int16_t)interval_draw(st, (uint32_t)(avail - 1));
  }
  return c;
}

constexpr Circuit CIRC = make_circuit();

// ---------------------------------------------------------------------------
// helpers
// ---------------------------------------------------------------------------
__device__ __forceinline__ uint16_t f2bf(float f) {
  uint32_t u = __builtin_bit_cast(uint32_t, f);
  uint32_t r = (u + 0x7fffu + ((u >> 16) & 1u)) >> 16;  // RNE
  return (uint16_t)r;
}
__device__ __forceinline__ float bf2f(uint16_t h) {
  uint32_t u = ((uint32_t)h) << 16;
  return __builtin_bit_cast(float, u);
}

__device__ __forceinline__ void load_lds16(const void* g, void* l) {
  __builtin_amdgcn_global_load_lds(
      (const __attribute__((address_space(1))) unsigned int*)g,
      (__attribute__((address_space(3))) unsigned int*)l, 16, 0, 0);
}

using bf16x8 = __attribute__((ext_vector_type(8))) short;
using f32x4  = __attribute__((ext_vector_type(4))) float;
using u16x8  = __attribute__((ext_vector_type(8))) unsigned short;
using u16x4  = __attribute__((ext_vector_type(4))) unsigned short;

// ds_read_b128 with compile-time offset immediate (no per-read VALU addr math)
template <int IMM>
__device__ __forceinline__ void dsr_i(bf16x8& d, uint32_t a) {
  asm volatile("ds_read_b128 %0, %1 offset:%2" : "=v"(d) : "v"(a), "n"(IMM));
}

// ---------------------------------------------------------------------------
// Circuit evaluation: fully unrolled, static indices only
// ---------------------------------------------------------------------------
template <int I>
__device__ __forceinline__ void eval_node(float (&vals)[N_VALS]) {
  if constexpr (I < N_INTERNAL) {
    constexpr int p0 = CIRC.prime[I][0], s0 = CIRC.sub[I][0];
    constexpr int p1 = CIRC.prime[I][1], s1 = CIRC.sub[I][1];
    constexpr int p2 = CIRC.prime[I][2], s2 = CIRC.sub[I][2];
    vals[2 * N_CLASSES + I] =
        vals[p0] * vals[s0] + vals[p1] * vals[s1] + vals[p2] * vals[s2];
    eval_node<I + 1>(vals);
  }
}

// ---------------------------------------------------------------------------
// fused prep kernel: blockIdx ranges map to three jobs
//   [0, B_SZ)                      : x row convert+pad  -> xb
//   [B_SZ, B_SZ+896)               : W1 64x64 transpose tile -> w1t
//   [B_SZ+896, B_SZ+896+4096)      : W2 64x64 transpose tile -> w2t
// ---------------------------------------------------------------------------
__device__ __forceinline__ void transpose_tile64(
    const float* __restrict__ W, uint16_t* __restrict__ Wt,
    int K, int N, int Kp, int kt, int nt, int t) {
  __shared__ float tile[64][65];
  const int lr = t >> 4;         // 0..15
  const int lc = (t & 15) * 4;   // 0..60
#pragma unroll
  for (int p = 0; p < 4; ++p) {
    const int row = lr + p * 16;
    const int k = kt + row;
    float4 v = {0.f, 0.f, 0.f, 0.f};
    if (k < K) v = *reinterpret_cast<const float4*>(W + (size_t)k * N + nt + lc);
    tile[row][lc + 0] = v.x;
    tile[row][lc + 1] = v.y;
    tile[row][lc + 2] = v.z;
    tile[row][lc + 3] = v.w;
  }
  __syncthreads();
  const int wn = t >> 3;        // 0..31
  const int k8 = (t & 7) * 8;   // 0..56
#pragma unroll
  for (int p = 0; p < 2; ++p) {
    const int n = nt + wn + 32 * p;
    u16x8 o;
#pragma unroll
    for (int i = 0; i < 8; ++i) o[i] = f2bf(tile[k8 + i][wn + 32 * p]);
    *reinterpret_cast<u16x8*>(Wt + (size_t)n * Kp + kt + k8) = o;
  }
}

__global__ __launch_bounds__(256) void prep_kernel(
    const float* __restrict__ x, const float* __restrict__ W1,
    const float* __restrict__ W2, uint16_t* __restrict__ xb,
    uint16_t* __restrict__ w1t, uint16_t* __restrict__ w2t) {
  const int b = blockIdx.x;
  const int t = threadIdx.x;
  if (b < B_SZ) {
    // x row convert+pad (float4 loads, 8B stores)
    if (t < D_IN / 4) {
      float4 v = *reinterpret_cast<const float4*>(x + (size_t)b * D_IN + t * 4);
      u16x4 o;
      o[0] = f2bf(v.x); o[1] = f2bf(v.y); o[2] = f2bf(v.z); o[3] = f2bf(v.w);
      *reinterpret_cast<u16x4*>(xb + (size_t)b * KP1 + t * 4) = o;
    } else if (t < KP1 / 4) {
      u16x4 z = {0, 0, 0, 0};
      *reinterpret_cast<u16x4*>(xb + (size_t)b * KP1 + t * 4) = z;
    }
  } else if (b < B_SZ + (KP1 / 64) * (H_DIM / 64)) {
    const int tt = b - B_SZ;                 // W1 tile
    const int nt = (tt & 63) * 64;           // H_DIM/64 = 64 tiles in n
    const int kt = (tt >> 6) * 64;           // KP1/64 = 14 tiles in k
    transpose_tile64(W1, w1t, D_IN, H_DIM, KP1, kt, nt, t);
  } else {
    const int tt = b - B_SZ - (KP1 / 64) * (H_DIM / 64);  // W2 tile
    const int nt = (tt & 63) * 64;
    const int kt = (tt >> 6) * 64;
    transpose_tile64(W2, w2t, H_DIM, H_DIM, H_DIM, kt, nt, t);
  }
}

// ---------------------------------------------------------------------------
// 256x256 8-phase bf16 MFMA GEMM — EXACT R10 kernel (verified: 221us @ L2,
// MfmaUtil 57%, SQ_LDS_BANK_CONFLICT 0, VGPR 120, no spill).
// R11's 32x32x16 variant REGRESSED: 32-distinct-row fragment reads conflict
// ~4-way under slot^=(row&7) (2.5e7 conflicts); 16x16's 16-row x 4-chunk
// pattern measures 0. Keep 16x16.
// ---------------------------------------------------------------------------
template <int MH, int NH, int BUF, bool RA, bool RB, int VM, typename F>
__device__ __forceinline__ void phase_t(
    uint32_t aA0, uint32_t aA1, uint32_t bA0, uint32_t bA1,
    bf16x8 (&Ar)[4][2], bf16x8 (&Br)[2][2][2], f32x4 (&acc)[2][2][4][2],
    F&& stage) {
  constexpr int AO = BUF * 32768 + MH * 16384;
  constexpr int BO = BUF * 32768 + NH * 16384;
  if constexpr (RA) {
    dsr_i<AO + 0 * 2048>(Ar[0][0], aA0); dsr_i<AO + 0 * 2048>(Ar[0][1], aA1);
    dsr_i<AO + 1 * 2048>(Ar[1][0], aA0); dsr_i<AO + 1 * 2048>(Ar[1][1], aA1);
    dsr_i<AO + 2 * 2048>(Ar[2][0], aA0); dsr_i<AO + 2 * 2048>(Ar[2][1], aA1);
    dsr_i<AO + 3 * 2048>(Ar[3][0], aA0); dsr_i<AO + 3 * 2048>(Ar[3][1], aA1);
  }
  if constexpr (RB) {
    dsr_i<BO + 0 * 2048>(Br[NH][0][0], bA0); dsr_i<BO + 0 * 2048>(Br[NH][0][1], bA1);
    dsr_i<BO + 1 * 2048>(Br[NH][1][0], bA0); dsr_i<BO + 1 * 2048>(Br[NH][1][1], bA1);
  }
  stage();
  asm volatile("s_waitcnt lgkmcnt(0)" ::: "memory");
  __builtin_amdgcn_sched_barrier(0);  // rule #18
  __builtin_amdgcn_s_setprio(1);
#pragma unroll
  for (int m = 0; m < 4; ++m)
#pragma unroll
    for (int nf = 0; nf < 2; ++nf) {
      acc[MH][NH][m][nf] = __builtin_amdgcn_mfma_f32_16x16x32_bf16(
          Ar[m][0], Br[NH][nf][0], acc[MH][NH][m][nf], 0, 0, 0);
      acc[MH][NH][m][nf] = __builtin_amdgcn_mfma_f32_16x16x32_bf16(
          Ar[m][1], Br[NH][nf][1], acc[MH][NH][m][nf], 0, 0, 0);
    }
  __builtin_amdgcn_s_setprio(0);
  if constexpr (VM >= 0) asm volatile("s_waitcnt vmcnt(%0)" :: "i"(VM) : "memory");
  __builtin_amdgcn_s_barrier();
}

__global__ __launch_bounds__(512, 1) void gemm256_bf16(
    const uint16_t* __restrict__ A, const uint16_t* __restrict__ Bt,
    const float* __restrict__ bias, uint16_t* __restrict__ C,
    int M, int N, int K) {
  extern __shared__ char smem[];

  const int t    = threadIdx.x;
  const int t16  = t * 16;
  const int lane = t & 63;
  const int wid  = t >> 6;
  const int wr   = wid >> 2;   // 0..1
  const int wc   = wid & 3;    // 0..3
  const int fr   = lane & 15;
  const int fq   = lane >> 4;

  const int gx = gridDim.x, gy = gridDim.y;
  const int nwg = gx * gy;
  const int id  = blockIdx.y * gx + blockIdx.x;
  const int cpx = nwg >> 3;
  const int sid = (id & 7) * cpx + (id >> 3);
  const int row0 = (sid / gx) * 256;
  const int col0 = (sid % gx) * 256;

  const uint32_t Kb = (uint32_t)K * 2;

  const char* gA = (const char*)A + (size_t)row0 * Kb;
  const char* gB = (const char*)Bt + (size_t)col0 * Kb;

  const uint32_t prow = (uint32_t)(t >> 3);
  const uint32_t sg   = (uint32_t)(((t & 7) ^ (t >> 3)) & 7) * 16u;
  const uint32_t srcA = prow * Kb + sg;
  const uint32_t srcB = (prow + 32u * (prow >> 5)) * Kb + sg;

#define ROWA(h, j) ((h) * 64 + (j) * 128)
#define ROWB(h, j) ((h) * 32 + (j) * 128)

#define STAGE_A(v, h, kt) do { \
    load_lds16(gA + (size_t)(kt) * 128 + (size_t)ROWA(h, 0) * Kb + srcA, \
               smem + (v) * 32768 + (h) * 16384 + t16); \
    load_lds16(gA + (size_t)(kt) * 128 + (size_t)ROWA(h, 1) * Kb + srcA, \
               smem + (v) * 32768 + (h) * 16384 + 8192 + t16); } while (0)
#define STAGE_B(v, h, kt) do { \
    load_lds16(gB + (size_t)(kt) * 128 + (size_t)ROWB(h, 0) * Kb + srcB, \
               smem + 65536 + (v) * 32768 + (h) * 16384 + t16); \
    load_lds16(gB + (size_t)(kt) * 128 + (size_t)ROWB(h, 1) * Kb + srcB, \
               smem + 65536 + (v) * 32768 + (h) * 16384 + 8192 + t16); } while (0)

  const uint32_t smb = (uint32_t)(size_t)(__attribute__((address_space(3))) char*)smem;
  const uint32_t s0v = (uint32_t)(((fq) ^ (fr & 7)) * 16);
  const uint32_t aA0 = smb + (uint32_t)((wr * 64 + fr) * 128) + s0v;
  const uint32_t aA1 = smb + (uint32_t)((wr * 64 + fr) * 128) + (s0v ^ 64u);
  const uint32_t bA0 = smb + 65536u + (uint32_t)((wc * 32 + fr) * 128) + s0v;
  const uint32_t bA1 = smb + 65536u + (uint32_t)((wc * 32 + fr) * 128) + (s0v ^ 64u);

  f32x4 acc[2][2][4][2];
#pragma unroll
  for (int a = 0; a < 2; ++a)
#pragma unroll
    for (int b = 0; b < 2; ++b)
#pragma unroll
      for (int m = 0; m < 4; ++m)
#pragma unroll
        for (int n = 0; n < 2; ++n) {
          acc[a][b][m][n][0] = 0.f; acc[a][b][m][n][1] = 0.f;
          acc[a][b][m][n][2] = 0.f; acc[a][b][m][n][3] = 0.f;
        }

  bf16x8 Ar[4][2], Br[2][2][2];

  STAGE_A(0, 0, 0); STAGE_B(0, 0, 0); STAGE_A(0, 1, 0); STAGE_B(0, 1, 0);
  STAGE_A(1, 0, 1); STAGE_B(1, 1, 1); STAGE_A(1, 1, 1);
  asm volatile("s_waitcnt vmcnt(6)" ::: "memory");
  __builtin_amdgcn_s_barrier();

#define PH(MH_, NH_, RA_, RB_, VM_, BUF_, ...) \
  phase_t<MH_, NH_, BUF_, RA_, RB_, VM_>(aA0, aA1, bA0, bA1, \
                                         Ar, Br, acc, [&]() { __VA_ARGS__ })

  const int NI = K >> 7;
  int i = 0;
  for (; i < NI - 1; ++i) {
    const int ktb = 2 * i + 1, ktc = 2 * i + 2, ktd = 2 * i + 3;
    PH(0, 0, true,  true,  -1, 0, STAGE_B(1, 0, ktb); );
    PH(0, 1, false, true,  -1, 0, STAGE_A(0, 0, ktc); );
    PH(1, 1, true,  false, -1, 0, STAGE_B(0, 1, ktc); );
    PH(1, 0, false, true,   6, 0, STAGE_A(0, 1, ktc); );
    PH(0, 0, true,  true,  -1, 1, STAGE_B(0, 0, ktc); );
    PH(0, 1, false, true,  -1, 1, STAGE_A(1, 0, ktd); );
    PH(1, 1, true,  false, -1, 1, STAGE_B(1, 1, ktd); );
    PH(1, 0, false, true,   6, 1, STAGE_A(1, 1, ktd); );
  }
  {
    const int ktb = 2 * i + 1;
    PH(0, 0, true,  true,  -1, 0, STAGE_B(1, 0, ktb); );
    PH(0, 1, false, true,  -1, 0, );
    PH(1, 1, true,  false, -1, 0, );
    PH(1, 0, false, true,   0, 0, );
    PH(0, 0, true,  true,  -1, 1, );
    PH(0, 1, false, true,  -1, 1, );
    PH(1, 1, true,  false, -1, 1, );
    PH(1, 0, false, true,  -1, 1, );
  }
#undef PH
#undef STAGE_A
#undef STAGE_B
#undef ROWA
#undef ROWB

  // epilogue: bias + relu + bf16 store; C/D: col=lane&15, row=(lane>>4)*4+j [m89]
#pragma unroll
  for (int mh = 0; mh < 2; ++mh)
#pragma unroll
    for (int nh = 0; nh < 2; ++nh)
#pragma unroll
      for (int m = 0; m < 4; ++m)
#pragma unroll
        for (int nf = 0; nf < 2; ++nf) {
          const int row = row0 + wr * 128 + mh * 64 + m * 16 + fq * 4;
          const int col = col0 + wc * 64 + nh * 32 + nf * 16 + fr;
          const float bv = bias[col];
          const size_t base = (size_t)row * N + col;
#pragma unroll
          for (int j = 0; j < 4; ++j) {
            float v = acc[mh][nh][m][nf][j] + bv;
            v = fmaxf(v, 0.0f);
            C[base + (size_t)j * N] = f2bf(v);
          }
        }
}

// ---------------------------------------------------------------------------
// fused logits (K=4096, N=10) + softmax + circuit -> out[B]; one wave per row.
// After the shfl_xor butterfly ALL lanes hold the full logit sums, so all
// lanes redundantly compute softmax + the unrolled circuit (static indices,
// register-resident); lane 0 writes. Removes probs round-trip + one launch.
// ---------------------------------------------------------------------------
__global__ __launch_bounds__(256) void logits_circuit_kernel(
    const uint16_t* __restrict__ h2, const float* __restrict__ W3,
    const float* __restrict__ b3, float* __restrict__ out, int B) {
  const int wave = threadIdx.x >> 6;
  const int lane = threadIdx.x & 63;
  const int row  = blockIdx.x * 4 + wave;
  if (row >= B) return;

  const uint16_t* hrow = h2 + (size_t)row * H_DIM;
  float acc[N_CLASSES];
#pragma unroll
  for (int c = 0; c < N_CLASSES; ++c) acc[c] = 0.0f;

#pragma unroll
  for (int it = 0; it < H_DIM / (64 * 8); ++it) {
    const int k0 = (it * 64 + lane) * 8;
    ushort4 u0 = *reinterpret_cast<const ushort4*>(hrow + k0);
    ushort4 u1 = *reinterpret_cast<const ushort4*>(hrow + k0 + 4);
    float hv[8] = {bf2f(u0.x), bf2f(u0.y), bf2f(u0.z), bf2f(u0.w),
                   bf2f(u1.x), bf2f(u1.y), bf2f(u1.z), bf2f(u1.w)};
#pragma unroll
    for (int q = 0; q < 8; ++q) {
      const float* wrow = W3 + (size_t)(k0 + q) * N_CLASSES;
#pragma unroll
      for (int c = 0; c < N_CLASSES; ++c) acc[c] = fmaf(hv[q], wrow[c], acc[c]);
    }
  }

#pragma unroll
  for (int c = 0; c < N_CLASSES; ++c) {
#pragma unroll
    for (int s = 32; s >= 1; s >>= 1) acc[c] += __shfl_xor(acc[c], s, 64);
  }

  // all lanes: softmax (identical values -> no divergence)
  float l[N_CLASSES], m = -3.0e38f;
#pragma unroll
  for (int c = 0; c < N_CLASSES; ++c) {
    l[c] = acc[c] + b3[c];
    m = fmaxf(m, l[c]);
  }
  float sum = 0.0f;
#pragma unroll
  for (int c = 0; c < N_CLASSES; ++c) {
    l[c] = expf(l[c] - m);
    sum += l[c];
  }
  const float inv = 1.0f / sum;

  // circuit eval in registers
  float vals[N_VALS];
#pragma unroll
  for (int c = 0; c < N_CLASSES; ++c) {
    const float p = l[c] * inv;
    vals[c] = p;
    vals[N_CLASSES + c] = 1.0f - p;
  }
  eval_node<0>(vals);
  if (lane == 0) out[row] = vals[N_VALS - 1];
}

// ---------------------------------------------------------------------------
// launch.  ws layout (bf16): xb[8192*896] w1t[4096*896] w2t[4096*4096]
//   h1[8192*4096] h2[8192*4096]   (~150 MB)
// 4 dispatches total (was 8): prep, gemm L1, gemm L2, logits+circuit.
// ---------------------------------------------------------------------------
extern "C" void kernel_launch(void* const* d_in, const int* in_sizes, int n_in,
                              void* d_out, int out_size, void* d_ws, size_t ws_size,
                              hipStream_t stream) {
  const float* x  = (const float*)d_in[0];
  const float* W1 = (const float*)d_in[1];
  const float* b1 = (const float*)d_in[2];
  const float* W2 = (const float*)d_in[3];
  const float* b2 = (const float*)d_in[4];
  const float* W3 = (const float*)d_in[5];
  const float* b3 = (const float*)d_in[6];
  float* out = (float*)d_out;

  uint16_t* xb  = (uint16_t*)d_ws;
  uint16_t* w1t = xb  + (size_t)B_SZ * KP1;
  uint16_t* w2t = w1t + (size_t)H_DIM * KP1;
  uint16_t* h1  = w2t + (size_t)H_DIM * H_DIM;
  uint16_t* h2  = h1  + (size_t)B_SZ * H_DIM;

  (void)hipFuncSetAttribute((const void*)gemm256_bf16,
                            hipFuncAttributeMaxDynamicSharedMemorySize, 131072);

  dim3 blk(256);

  // fused prep: x convert (8192 blocks) + W1 tiles (896) + W2 tiles (4096)
  const int prep_blocks = B_SZ + (KP1 / 64) * (H_DIM / 64) + (H_DIM / 64) * (H_DIM / 64);
  prep_kernel<<<dim3(prep_blocks), blk, 0, stream>>>(x, W1, W2, xb, w1t, w2t);

  // layer 1: h1 = relu(xb @ w1t^T + b1)   [8192,896]x[896,4096]
  gemm256_bf16<<<dim3(H_DIM / 256, B_SZ / 256), dim3(512), 131072, stream>>>(
      xb, w1t, b1, h1, B_SZ, H_DIM, KP1);

  // layer 2: h2 = relu(h1 @ w2t^T + b2)   [8192,4096]x[4096,4096]
  gemm256_bf16<<<dim3(H_DIM / 256, B_SZ / 256), dim3(512), 131072, stream>>>(
      h1, w2t, b2, h2, B_SZ, H_DIM, H_DIM);

  // layer 3 + softmax + circuit -> out[B]
  logits_circuit_kernel<<<dim3(B_SZ / 4), blk, 0, stream>>>(h2, W3, b3, out, B_SZ);
}

// Round 13
// 353.034 us; speedup vs baseline: 1.2705x; 1.1464x over previous
//
#include <hip/hip_runtime.h>
#include <cstdint>
#include <cstddef>

// ---------------------------------------------------------------------------
// Problem constants
// ---------------------------------------------------------------------------
constexpr int N_CLASSES  = 10;
constexpr int N_INTERNAL = 256;
constexpr int N_VALS     = 2 * N_CLASSES + N_INTERNAL;  // 276
constexpr int B_SZ  = 8192;
constexpr int D_IN  = 784;
constexpr int KP1   = 896;    // D_IN padded to multiple of 128
constexpr int H_DIM = 4096;

// ---------------------------------------------------------------------------
// Compile-time reconstruction of np.random.RandomState(0) circuit generation.
// (verified bit-exact in round 2: absmax == 0.0)
// ---------------------------------------------------------------------------
struct MTState {
  uint32_t key[624];
  int pos;
};

constexpr uint32_t mt_next(MTState& st) {
  if (st.pos == 624) {
    for (int i = 0; i < 624; ++i) {
      uint32_t y = (st.key[i] & 0x80000000u) | (st.key[(i + 1) % 624] & 0x7fffffffu);
      st.key[i] = st.key[(i + 397) % 624] ^ (y >> 1) ^ ((y & 1u) ? 0x9908b0dfu : 0u);
    }
    st.pos = 0;
  }
  uint32_t y = st.key[st.pos++];
  y ^= y >> 11;
  y ^= (y << 7) & 0x9d2c5680u;
  y ^= (y << 15) & 0xefc60000u;
  y ^= y >> 18;
  return y;
}

constexpr uint32_t interval_draw(MTState& st, uint32_t maxv) {
  if (maxv == 0u) return 0u;
  uint32_t mask = maxv;
  mask |= mask >> 1; mask |= mask >> 2; mask |= mask >> 4;
  mask |= mask >> 8; mask |= mask >> 16;
  uint32_t v = mt_next(st) & mask;
  while (v > maxv) v = mt_next(st) & mask;
  return v;
}

struct Circuit {
  int16_t prime[N_INTERNAL][3];
  int16_t sub[N_INTERNAL][3];
};

constexpr Circuit make_circuit() {
  MTState st{};
  uint32_t s = 0u;
  for (int i = 0; i < 624; ++i) {
    st.key[i] = s;
    s = 1812433253u * (s ^ (s >> 30)) + (uint32_t)i + 1u;
  }
  st.pos = 624;

  Circuit c{};
  for (int node = 0; node < N_INTERNAL; ++node) {
    const int avail = 2 * N_CLASSES + node;
    int arr[N_CLASSES] = {0, 1, 2, 3, 4, 5, 6, 7, 8, 9};
    for (int i = N_CLASSES - 1; i >= 1; --i) {
      uint32_t j = interval_draw(st, (uint32_t)i);
      int tmp = arr[i]; arr[i] = arr[j]; arr[j] = tmp;
    }
    for (int e = 0; e < 3; ++e) c.prime[node][e] = (int16_t)arr[e];
    for (int e = 0; e < 3; ++e) c.sub[node][e] = (int16_t)interval_draw(st, (uint32_t)(avail - 1));
  }
  return c;
}

constexpr Circuit CIRC = make_circuit();

// ---------------------------------------------------------------------------
// helpers
// ---------------------------------------------------------------------------
__device__ __forceinline__ uint16_t f2bf(float f) {
  uint32_t u = __builtin_bit_cast(uint32_t, f);
  uint32_t r = (u + 0x7fffu + ((u >> 16) & 1u)) >> 16;  // RNE
  return (uint16_t)r;
}
__device__ __forceinline__ float bf2f(uint16_t h) {
  uint32_t u = ((uint32_t)h) << 16;
  return __builtin_bit_cast(float, u);
}

__device__ __forceinline__ void load_lds16(const void* g, void* l) {
  __builtin_amdgcn_global_load_lds(
      (const __attribute__((address_space(1))) unsigned int*)g,
      (__attribute__((address_space(3))) unsigned int*)l, 16, 0, 0);
}

using bf16x8 = __attribute__((ext_vector_type(8))) short;
using f32x4  = __attribute__((ext_vector_type(4))) float;
using u16x8  = __attribute__((ext_vector_type(8))) unsigned short;
using u16x4  = __attribute__((ext_vector_type(4))) unsigned short;

// ds_read_b128 with compile-time offset immediate (no per-read VALU addr math)
template <int IMM>
__device__ __forceinline__ void dsr_i(bf16x8& d, uint32_t a) {
  asm volatile("ds_read_b128 %0, %1 offset:%2" : "=v"(d) : "v"(a), "n"(IMM));
}

// ---------------------------------------------------------------------------
// Circuit evaluation: fully unrolled, static indices only
// ---------------------------------------------------------------------------
template <int I>
__device__ __forceinline__ void eval_node(float (&vals)[N_VALS]) {
  if constexpr (I < N_INTERNAL) {
    constexpr int p0 = CIRC.prime[I][0], s0 = CIRC.sub[I][0];
    constexpr int p1 = CIRC.prime[I][1], s1 = CIRC.sub[I][1];
    constexpr int p2 = CIRC.prime[I][2], s2 = CIRC.sub[I][2];
    vals[2 * N_CLASSES + I] =
        vals[p0] * vals[s0] + vals[p1] * vals[s1] + vals[p2] * vals[s2];
    eval_node<I + 1>(vals);
  }
}

// ---------------------------------------------------------------------------
// fused prep kernel: blockIdx ranges map to four jobs
//   [0, 8192)            : x row convert+pad  -> xb
//   [8192, 8192+896)     : W1 64x64 transpose tile -> w1t (bf16)
//   [9088, 9088+4096)    : W2 64x64 transpose tile -> w2t (bf16)
//   [13184, 13184+16)    : W3 transpose -> w3t f32[10][4096] (256 rows/block)
// ---------------------------------------------------------------------------
__device__ __forceinline__ void transpose_tile64(
    const float* __restrict__ W, uint16_t* __restrict__ Wt,
    int K, int N, int Kp, int kt, int nt, int t) {
  __shared__ float tile[64][65];
  const int lr = t >> 4;         // 0..15
  const int lc = (t & 15) * 4;   // 0..60
#pragma unroll
  for (int p = 0; p < 4; ++p) {
    const int row = lr + p * 16;
    const int k = kt + row;
    float4 v = {0.f, 0.f, 0.f, 0.f};
    if (k < K) v = *reinterpret_cast<const float4*>(W + (size_t)k * N + nt + lc);
    tile[row][lc + 0] = v.x;
    tile[row][lc + 1] = v.y;
    tile[row][lc + 2] = v.z;
    tile[row][lc + 3] = v.w;
  }
  __syncthreads();
  const int wn = t >> 3;        // 0..31
  const int k8 = (t & 7) * 8;   // 0..56
#pragma unroll
  for (int p = 0; p < 2; ++p) {
    const int n = nt + wn + 32 * p;
    u16x8 o;
#pragma unroll
    for (int i = 0; i < 8; ++i) o[i] = f2bf(tile[k8 + i][wn + 32 * p]);
    *reinterpret_cast<u16x8*>(Wt + (size_t)n * Kp + kt + k8) = o;
  }
}

__global__ __launch_bounds__(256) void prep_kernel(
    const float* __restrict__ x, const float* __restrict__ W1,
    const float* __restrict__ W2, const float* __restrict__ W3,
    uint16_t* __restrict__ xb, uint16_t* __restrict__ w1t,
    uint16_t* __restrict__ w2t, float* __restrict__ w3t) {
  const int b = blockIdx.x;
  const int t = threadIdx.x;
  constexpr int W1_T = (KP1 / 64) * (H_DIM / 64);    // 896
  constexpr int W2_T = (H_DIM / 64) * (H_DIM / 64);  // 4096
  if (b < B_SZ) {
    if (t < D_IN / 4) {
      float4 v = *reinterpret_cast<const float4*>(x + (size_t)b * D_IN + t * 4);
      u16x4 o;
      o[0] = f2bf(v.x); o[1] = f2bf(v.y); o[2] = f2bf(v.z); o[3] = f2bf(v.w);
      *reinterpret_cast<u16x4*>(xb + (size_t)b * KP1 + t * 4) = o;
    } else if (t < KP1 / 4) {
      u16x4 z = {0, 0, 0, 0};
      *reinterpret_cast<u16x4*>(xb + (size_t)b * KP1 + t * 4) = z;
    }
  } else if (b < B_SZ + W1_T) {
    const int tt = b - B_SZ;
    transpose_tile64(W1, w1t, D_IN, H_DIM, KP1, (tt >> 6) * 64, (tt & 63) * 64, t);
  } else if (b < B_SZ + W1_T + W2_T) {
    const int tt = b - B_SZ - W1_T;
    transpose_tile64(W2, w2t, H_DIM, H_DIM, H_DIM, (tt >> 6) * 64, (tt & 63) * 64, t);
  } else {
    // W3 [4096][10] -> w3t [10][4096]
    const int row = (b - B_SZ - W1_T - W2_T) * 256 + t;
#pragma unroll
    for (int c = 0; c < N_CLASSES; ++c)
      w3t[(size_t)c * H_DIM + row] = W3[(size_t)row * N_CLASSES + c];
  }
}

// ---------------------------------------------------------------------------
// 256x256 8-phase bf16 MFMA GEMM (R10 sync structure + intra-phase split-wait):
//   C[M,N] = relu(A[M,K] @ Bt[N,K]^T + bias[N]), bf16 in/out, f32 accum.
// 512 threads = 8 waves (2Mx4N). BK=64, 2 K-tiles/iter, 8 phases/iter,
// quadrant order (00),(01),(11),(10); B0 re-read in phase 4.
// NEW (R13): within each phase, reads grouped by k-slice; lgkmcnt(S1) after
// slice-0 reads -> slice-0 MFMAs overlap slice-1 read latency; stage() issued
// FIRST in the phase (earlier VMEM; FIFO order across phases unchanged, so
// the vmcnt(6) proof from R8 holds verbatim). Per-accumulator summation
// order unchanged (s0 then s1) -> bit-identical output.
// ONE barrier per phase (post-MFMA); WAR/RAW safety per R9 analysis.
// VGPR ~120 < 128 (no spill); LDS 128 KiB; slot^=(row&7) XOR swizzle;
// linear LDS dest + inverse-swizzled per-lane global source.
// Requires: M%256==0, N%256==0, K%128==0, K>=256.
// R12 baseline: 220us @ L2, MfmaUtil 57%, conflicts 0.
// ---------------------------------------------------------------------------
template <int MH, int NH, int BUF, bool RA, bool RB, int VM, typename F>
__device__ __forceinline__ void phase_t(
    uint32_t aA0, uint32_t aA1, uint32_t bA0, uint32_t bA1,
    bf16x8 (&Ar)[4][2], bf16x8 (&Br)[2][2][2], f32x4 (&acc)[2][2][4][2],
    F&& stage) {
  constexpr int AO = BUF * 32768 + MH * 16384;
  constexpr int BO = BUF * 32768 + NH * 16384;
  // 0. issue this phase's global_load_lds first (VMEM issue under reads/MFMA)
  stage();
  // 1. slice-0 ds_reads, then slice-1 ds_reads (volatile asm, program order)
  if constexpr (RA) {
    dsr_i<AO + 0 * 2048>(Ar[0][0], aA0);
    dsr_i<AO + 1 * 2048>(Ar[1][0], aA0);
    dsr_i<AO + 2 * 2048>(Ar[2][0], aA0);
    dsr_i<AO + 3 * 2048>(Ar[3][0], aA0);
  }
  if constexpr (RB) {
    dsr_i<BO + 0 * 2048>(Br[NH][0][0], bA0);
    dsr_i<BO + 1 * 2048>(Br[NH][1][0], bA0);
  }
  if constexpr (RA) {
    dsr_i<AO + 0 * 2048>(Ar[0][1], aA1);
    dsr_i<AO + 1 * 2048>(Ar[1][1], aA1);
    dsr_i<AO + 2 * 2048>(Ar[2][1], aA1);
    dsr_i<AO + 3 * 2048>(Ar[3][1], aA1);
  }
  if constexpr (RB) {
    dsr_i<BO + 0 * 2048>(Br[NH][0][1], bA1);
    dsr_i<BO + 1 * 2048>(Br[NH][1][1], bA1);
  }
  // 2. wait slice-0 only (S1 = slice-1 reads still outstanding); MFMA slice 0
  constexpr int S1 = (RA ? 4 : 0) + (RB ? 2 : 0);
  asm volatile("s_waitcnt lgkmcnt(%0)" :: "i"(S1) : "memory");
  __builtin_amdgcn_sched_barrier(0);  // rule #18
  __builtin_amdgcn_s_setprio(1);
#pragma unroll
  for (int m = 0; m < 4; ++m)
#pragma unroll
    for (int nf = 0; nf < 2; ++nf)
      acc[MH][NH][m][nf] = __builtin_amdgcn_mfma_f32_16x16x32_bf16(
          Ar[m][0], Br[NH][nf][0], acc[MH][NH][m][nf], 0, 0, 0);
  // 3. wait slice-1; MFMA slice 1
  asm volatile("s_waitcnt lgkmcnt(0)" ::: "memory");
  __builtin_amdgcn_sched_barrier(0);
#pragma unroll
  for (int m = 0; m < 4; ++m)
#pragma unroll
    for (int nf = 0; nf < 2; ++nf)
      acc[MH][NH][m][nf] = __builtin_amdgcn_mfma_f32_16x16x32_bf16(
          Ar[m][1], Br[NH][nf][1], acc[MH][NH][m][nf], 0, 0, 0);
  __builtin_amdgcn_s_setprio(0);
  // 4. counted vmcnt (confirms the tile read after the NEXT barrier)
  if constexpr (VM >= 0) asm volatile("s_waitcnt vmcnt(%0)" :: "i"(VM) : "memory");
  __builtin_amdgcn_s_barrier();
}

__global__ __launch_bounds__(512, 1) void gemm256_bf16(
    const uint16_t* __restrict__ A, const uint16_t* __restrict__ Bt,
    const float* __restrict__ bias, uint16_t* __restrict__ C,
    int M, int N, int K) {
  extern __shared__ char smem[];

  const int t    = threadIdx.x;
  const int t16  = t * 16;
  const int lane = t & 63;
  const int wid  = t >> 6;
  const int wr   = wid >> 2;   // 0..1
  const int wc   = wid & 3;    // 0..3
  const int fr   = lane & 15;
  const int fq   = lane >> 4;

  const int gx = gridDim.x, gy = gridDim.y;
  const int nwg = gx * gy;
  const int id  = blockIdx.y * gx + blockIdx.x;
  const int cpx = nwg >> 3;
  const int sid = (id & 7) * cpx + (id >> 3);
  const int row0 = (sid / gx) * 256;
  const int col0 = (sid % gx) * 256;

  const uint32_t Kb = (uint32_t)K * 2;

  const char* gA = (const char*)A + (size_t)row0 * Kb;
  const char* gB = (const char*)Bt + (size_t)col0 * Kb;

  const uint32_t prow = (uint32_t)(t >> 3);
  const uint32_t sg   = (uint32_t)(((t & 7) ^ (t >> 3)) & 7) * 16u;
  const uint32_t srcA = prow * Kb + sg;
  const uint32_t srcB = (prow + 32u * (prow >> 5)) * Kb + sg;

#define ROWA(h, j) ((h) * 64 + (j) * 128)
#define ROWB(h, j) ((h) * 32 + (j) * 128)

#define STAGE_A(v, h, kt) do { \
    load_lds16(gA + (size_t)(kt) * 128 + (size_t)ROWA(h, 0) * Kb + srcA, \
               smem + (v) * 32768 + (h) * 16384 + t16); \
    load_lds16(gA + (size_t)(kt) * 128 + (size_t)ROWA(h, 1) * Kb + srcA, \
               smem + (v) * 32768 + (h) * 16384 + 8192 + t16); } while (0)
#define STAGE_B(v, h, kt) do { \
    load_lds16(gB + (size_t)(kt) * 128 + (size_t)ROWB(h, 0) * Kb + srcB, \
               smem + 65536 + (v) * 32768 + (h) * 16384 + t16); \
    load_lds16(gB + (size_t)(kt) * 128 + (size_t)ROWB(h, 1) * Kb + srcB, \
               smem + 65536 + (v) * 32768 + (h) * 16384 + 8192 + t16); } while (0)

  const uint32_t smb = (uint32_t)(size_t)(__attribute__((address_space(3))) char*)smem;
  const uint32_t s0v = (uint32_t)(((fq) ^ (fr & 7)) * 16);
  const uint32_t aA0 = smb + (uint32_t)((wr * 64 + fr) * 128) + s0v;
  const uint32_t aA1 = smb + (uint32_t)((wr * 64 + fr) * 128) + (s0v ^ 64u);
  const uint32_t bA0 = smb + 65536u + (uint32_t)((wc * 32 + fr) * 128) + s0v;
  const uint32_t bA1 = smb + 65536u + (uint32_t)((wc * 32 + fr) * 128) + (s0v ^ 64u);

  f32x4 acc[2][2][4][2];
#pragma unroll
  for (int a = 0; a < 2; ++a)
#pragma unroll
    for (int b = 0; b < 2; ++b)
#pragma unroll
      for (int m = 0; m < 4; ++m)
#pragma unroll
        for (int n = 0; n < 2; ++n) {
          acc[a][b][m][n][0] = 0.f; acc[a][b][m][n][1] = 0.f;
          acc[a][b][m][n][2] = 0.f; acc[a][b][m][n][3] = 0.f;
        }

  bf16x8 Ar[4][2], Br[2][2][2];

  STAGE_A(0, 0, 0); STAGE_B(0, 0, 0); STAGE_A(0, 1, 0); STAGE_B(0, 1, 0);
  STAGE_A(1, 0, 1); STAGE_B(1, 1, 1); STAGE_A(1, 1, 1);
  asm volatile("s_waitcnt vmcnt(6)" ::: "memory");
  __builtin_amdgcn_s_barrier();

#define PH(MH_, NH_, RA_, RB_, VM_, BUF_, ...) \
  phase_t<MH_, NH_, BUF_, RA_, RB_, VM_>(aA0, aA1, bA0, bA1, \
                                         Ar, Br, acc, [&]() { __VA_ARGS__ })

  const int NI = K >> 7;
  int i = 0;
  for (; i < NI - 1; ++i) {
    const int ktb = 2 * i + 1, ktc = 2 * i + 2, ktd = 2 * i + 3;
    PH(0, 0, true,  true,  -1, 0, STAGE_B(1, 0, ktb); );
    PH(0, 1, false, true,  -1, 0, STAGE_A(0, 0, ktc); );
    PH(1, 1, true,  false, -1, 0, STAGE_B(0, 1, ktc); );
    PH(1, 0, false, true,   6, 0, STAGE_A(0, 1, ktc); );
    PH(0, 0, true,  true,  -1, 1, STAGE_B(0, 0, ktc); );
    PH(0, 1, false, true,  -1, 1, STAGE_A(1, 0, ktd); );
    PH(1, 1, true,  false, -1, 1, STAGE_B(1, 1, ktd); );
    PH(1, 0, false, true,   6, 1, STAGE_A(1, 1, ktd); );
  }
  {
    const int ktb = 2 * i + 1;
    PH(0, 0, true,  true,  -1, 0, STAGE_B(1, 0, ktb); );
    PH(0, 1, false, true,  -1, 0, );
    PH(1, 1, true,  false, -1, 0, );
    PH(1, 0, false, true,   0, 0, );
    PH(0, 0, true,  true,  -1, 1, );
    PH(0, 1, false, true,  -1, 1, );
    PH(1, 1, true,  false, -1, 1, );
    PH(1, 0, false, true,  -1, 1, );
  }
#undef PH
#undef STAGE_A
#undef STAGE_B
#undef ROWA
#undef ROWB

  // epilogue: bias + relu + bf16 store; C/D: col=lane&15, row=(lane>>4)*4+j [m89]
#pragma unroll
  for (int mh = 0; mh < 2; ++mh)
#pragma unroll
    for (int nh = 0; nh < 2; ++nh)
#pragma unroll
      for (int m = 0; m < 4; ++m)
#pragma unroll
        for (int nf = 0; nf < 2; ++nf) {
          const int row = row0 + wr * 128 + mh * 64 + m * 16 + fq * 4;
          const int col = col0 + wc * 64 + nh * 32 + nf * 16 + fr;
          const float bv = bias[col];
          const size_t base = (size_t)row * N + col;
#pragma unroll
          for (int j = 0; j < 4; ++j) {
            float v = acc[mh][nh][m][nf][j] + bv;
            v = fmaxf(v, 0.0f);
            C[base + (size_t)j * N] = f2bf(v);
          }
        }
}

// ---------------------------------------------------------------------------
// fused logits (K=4096, N=10) + softmax + circuit -> out[B]; one wave per row.
// W3 consumed TRANSPOSED (w3t[10][4096] f32): per c, two coalesced float4
// loads per 8-k chunk (R12's wrow[c] form was 80 scalar lane-divergent loads
// per chunk). After the shfl_xor butterfly all lanes hold full sums; all
// lanes redundantly compute softmax+circuit (no divergence), lane 0 writes.
// ---------------------------------------------------------------------------
__global__ __launch_bounds__(256) void logits_circuit_kernel(
    const uint16_t* __restrict__ h2, const float* __restrict__ w3t,
    const float* __restrict__ b3, float* __restrict__ out, int B) {
  const int wave = threadIdx.x >> 6;
  const int lane = threadIdx.x & 63;
  const int row  = blockIdx.x * 4 + wave;
  if (row >= B) return;

  const uint16_t* hrow = h2 + (size_t)row * H_DIM;
  float acc[N_CLASSES];
#pragma unroll
  for (int c = 0; c < N_CLASSES; ++c) acc[c] = 0.0f;

#pragma unroll
  for (int it = 0; it < H_DIM / (64 * 8); ++it) {
    const int k0 = (it * 64 + lane) * 8;
    ushort4 u0 = *reinterpret_cast<const ushort4*>(hrow + k0);
    ushort4 u1 = *reinterpret_cast<const ushort4*>(hrow + k0 + 4);
    const float hv[8] = {bf2f(u0.x), bf2f(u0.y), bf2f(u0.z), bf2f(u0.w),
                         bf2f(u1.x), bf2f(u1.y), bf2f(u1.z), bf2f(u1.w)};
#pragma unroll
    for (int c = 0; c < N_CLASSES; ++c) {
      const float* wr = w3t + (size_t)c * H_DIM + k0;
      float4 w0 = *reinterpret_cast<const float4*>(wr);
      float4 w1 = *reinterpret_cast<const float4*>(wr + 4);
      float a = acc[c];
      a = fmaf(hv[0], w0.x, a); a = fmaf(hv[1], w0.y, a);
      a = fmaf(hv[2], w0.z, a); a = fmaf(hv[3], w0.w, a);
      a = fmaf(hv[4], w1.x, a); a = fmaf(hv[5], w1.y, a);
      a = fmaf(hv[6], w1.z, a); a = fmaf(hv[7], w1.w, a);
      acc[c] = a;
    }
  }

#pragma unroll
  for (int c = 0; c < N_CLASSES; ++c) {
#pragma unroll
    for (int s = 32; s >= 1; s >>= 1) acc[c] += __shfl_xor(acc[c], s, 64);
  }

  float l[N_CLASSES], m = -3.0e38f;
#pragma unroll
  for (int c = 0; c < N_CLASSES; ++c) {
    l[c] = acc[c] + b3[c];
    m = fmaxf(m, l[c]);
  }
  float sum = 0.0f;
#pragma unroll
  for (int c = 0; c < N_CLASSES; ++c) {
    l[c] = expf(l[c] - m);
    sum += l[c];
  }
  const float inv = 1.0f / sum;

  float vals[N_VALS];
#pragma unroll
  for (int c = 0; c < N_CLASSES; ++c) {
    const float p = l[c] * inv;
    vals[c] = p;
    vals[N_CLASSES + c] = 1.0f - p;
  }
  eval_node<0>(vals);
  if (lane == 0) out[row] = vals[N_VALS - 1];
}

// ---------------------------------------------------------------------------
// launch.  ws layout: xb[8192*896] w1t[4096*896] w2t[4096*4096]
//   h1[8192*4096] h2[8192*4096] (bf16) + w3t f32[10*4096]   (~150 MB)
// 4 dispatches: prep, gemm L1, gemm L2, logits+circuit.
// ---------------------------------------------------------------------------
extern "C" void kernel_launch(void* const* d_in, const int* in_sizes, int n_in,
                              void* d_out, int out_size, void* d_ws, size_t ws_size,
                              hipStream_t stream) {
  const float* x  = (const float*)d_in[0];
  const float* W1 = (const float*)d_in[1];
  const float* b1 = (const float*)d_in[2];
  const float* W2 = (const float*)d_in[3];
  const float* b2 = (const float*)d_in[4];
  const float* W3 = (const float*)d_in[5];
  const float* b3 = (const float*)d_in[6];
  float* out = (float*)d_out;

  uint16_t* xb  = (uint16_t*)d_ws;
  uint16_t* w1t = xb  + (size_t)B_SZ * KP1;
  uint16_t* w2t = w1t + (size_t)H_DIM * KP1;
  uint16_t* h1  = w2t + (size_t)H_DIM * H_DIM;
  uint16_t* h2  = h1  + (size_t)B_SZ * H_DIM;
  float* w3t    = (float*)(h2 + (size_t)B_SZ * H_DIM);

  (void)hipFuncSetAttribute((const void*)gemm256_bf16,
                            hipFuncAttributeMaxDynamicSharedMemorySize, 131072);

  dim3 blk(256);

  // fused prep: x (8192) + W1 tiles (896) + W2 tiles (4096) + W3 (16)
  const int prep_blocks =
      B_SZ + (KP1 / 64) * (H_DIM / 64) + (H_DIM / 64) * (H_DIM / 64) + H_DIM / 256;
  prep_kernel<<<dim3(prep_blocks), blk, 0, stream>>>(x, W1, W2, W3, xb, w1t, w2t, w3t);

  // layer 1: h1 = relu(xb @ w1t^T + b1)   [8192,896]x[896,4096]
  gemm256_bf16<<<dim3(H_DIM / 256, B_SZ / 256), dim3(512), 131072, stream>>>(
      xb, w1t, b1, h1, B_SZ, H_DIM, KP1);

  // layer 2: h2 = relu(h1 @ w2t^T + b2)   [8192,4096]x[4096,4096]
  gemm256_bf16<<<dim3(H_DIM / 256, B_SZ / 256), dim3(512), 131072, stream>>>(
      h1, w2t, b2, h2, B_SZ, H_DIM, H_DIM);

  // layer 3 + softmax + circuit -> out[B]
  logits_circuit_kernel<<<dim3(B_SZ / 4), blk, 0, stream>>>(h2, w3t, b3, out, B_SZ);
}